// Round 11
// baseline (380.802 us; speedup 1.0000x reference)
//
#include <hip/hip_runtime.h>
#include <math.h>

#define NN 50000
#define EE 400000
#define HD 256
#define NH 4
#define DH 64
#define NEG_SLOPE 0.2f
#define NTILES 3125   // 50000/16 exact

typedef __attribute__((ext_vector_type(8))) _Float16 f16x8;
typedef __attribute__((ext_vector_type(4))) float f32x4;

__device__ __forceinline__ float bf2f(unsigned short h) {
  return __uint_as_float(((unsigned)h) << 16);
}

// ============================ CSR build (scan-free) ============================
__global__ void k_zero_i32(int* __restrict__ p, int n) {
  int i = blockIdx.x * blockDim.x + threadIdx.x;
  if (i < n) p[i] = 0;
}

__global__ void k_count(const int* __restrict__ dst, int* __restrict__ counts,
                        int* __restrict__ rank) {
  int e = blockIdx.x * blockDim.x + threadIdx.x;
  if (e < EE) rank[e] = atomicAdd(&counts[dst[e]], 1);
}

__global__ void k_alloc(const int* __restrict__ counts, int* __restrict__ rstart,
                        int* __restrict__ total) {
  int i = blockIdx.x * blockDim.x + threadIdx.x;
  if (i < NN) rstart[i] = atomicAdd(total, counts[i]);
}

__global__ void k_scatter(const int* __restrict__ src, const int* __restrict__ dst,
                          const int* __restrict__ rstart, const int* __restrict__ rank,
                          int* __restrict__ csr_src) {
  int e = blockIdx.x * blockDim.x + threadIdx.x;
  if (e < EE) csr_src[rstart[dst[e]] + rank[e]] = src[e];
}

// ============================ W prep (fp16, pre-tiled) ============================
__global__ __launch_bounds__(256) void k_prep_w2(const float* __restrict__ W1,
                                                 const float* __restrict__ W2,
                                                 _Float16* __restrict__ W1t,
                                                 _Float16* __restrict__ W2t) {
  int b = blockIdx.x;
  const float* W = (b < 256) ? W1 : W2;
  _Float16* Wt = (b < 256) ? W1t : W2t;
  int t = (b & 255) * 256 + threadIdx.x;  // 65536
  int n = t & 255, k = t >> 8;
  float x = W[(size_t)k * 256 + n];
  size_t o = (size_t)(k >> 5) * 8192 + (size_t)((k >> 3) & 3) * 2048 + (size_t)n * 8 + (k & 7);
  Wt[o] = (_Float16)x;
}

// ============================ MFMA GEMM ============================
// fsl[8][NN][32](bf16) = A[idx[m],256] @ W ; fp16-split A: (Ah+Al)@W(fp16).
// Whole W (128KB fp16) in LDS, staged once, ONE barrier. Slice-major C store.
__device__ __forceinline__ void gload_lds16(const void* g, void* l) {
  __builtin_amdgcn_global_load_lds((const __attribute__((address_space(1))) void*)g,
                                   (__attribute__((address_space(3))) void*)l, 16, 0, 0);
}

__global__ __launch_bounds__(768, 3) void k_gemm_mfma(
    const float* __restrict__ A, const int* __restrict__ idx,
    const _Float16* __restrict__ Wt,
    const float* __restrict__ al, const float* __restrict__ ar,
    __bf16* __restrict__ fsl, float* __restrict__ el, float* __restrict__ er) {
  __shared__ f16x8 Bs[8192];  // 128KB

  int tid = threadIdx.x;
  int lane = tid & 63;
  int w = tid >> 6;           // 0..11
  int khalf = lane >> 4;
  int l15 = lane & 15;

  for (int i = tid; i < 8192; i += 768)
    gload_lds16(Wt + (size_t)i * 8, (void*)&Bs[i]);

  float alv[16], arv[16];
#pragma unroll
  for (int nf = 0; nf < 16; ++nf) {
    alv[nf] = al[nf * 16 + l15];
    arv[nf] = ar[nf * 16 + l15];
  }

  int nt = 1;
  int tiles[2];
  tiles[0] = blockIdx.x * 12 + w;
  int t2 = 3072 + blockIdx.x;
  if (w == 0 && t2 < NTILES) { tiles[1] = t2; nt = 2; }

  __syncthreads();  // the only barrier

  for (int it = 0; it < nt; ++it) {
    int t = tiles[it];
    int row = t * 16 + l15;
    int arow = idx ? idx[row] : row;
    const float* ap = A + (size_t)arow * HD + khalf * 8;

    f32x4 acc[16];
#pragma unroll
    for (int nf = 0; nf < 16; ++nf) acc[nf] = (f32x4){0.f, 0.f, 0.f, 0.f};

#pragma unroll 2
    for (int kb = 0; kb < 8; ++kb) {
      float xx[8];
      *(float4*)&xx[0] = *(const float4*)(ap + kb * 32);
      *(float4*)&xx[4] = *(const float4*)(ap + kb * 32 + 4);
      f16x8 ah, alo;
#pragma unroll
      for (int i = 0; i < 8; ++i) {
        _Float16 h = (_Float16)xx[i];
        ah[i] = h;
        alo[i] = (_Float16)(xx[i] - (float)h);
      }
#pragma unroll
      for (int nf = 0; nf < 16; ++nf) {
        f16x8 bv = Bs[kb * 1024 + khalf * 256 + nf * 16 + l15];
        acc[nf] = __builtin_amdgcn_mfma_f32_16x16x32_f16(ah, bv, acc[nf], 0, 0, 0);
        acc[nf] = __builtin_amdgcn_mfma_f32_16x16x32_f16(alo, bv, acc[nf], 0, 0, 0);
      }
    }

    int rowbase = t * 16 + khalf * 4;
#pragma unroll
    for (int r = 0; r < 4; ++r) {
      int row_ = rowbase + r;
      float seh[4], srh[4];
#pragma unroll
      for (int h = 0; h < 4; ++h) {
        float s1 = 0.f, s2 = 0.f;
#pragma unroll
        for (int j = 0; j < 4; ++j) {
          int nf = h * 4 + j;
          float v = acc[nf][r];
          s1 = fmaf(v, alv[nf], s1);
          s2 = fmaf(v, arv[nf], s2);
          // slice-major: slice = nf>>1, within = (nf&1)*16 + l15
          fsl[(size_t)(nf >> 1) * NN * 32 + (size_t)row_ * 32 + (nf & 1) * 16 + l15] = (__bf16)v;
        }
#pragma unroll
        for (int off = 1; off < 16; off <<= 1) {
          s1 += __shfl_xor(s1, off);
          s2 += __shfl_xor(s2, off);
        }
        seh[h] = s1;
        srh[h] = s2;
      }
      if (l15 == 0) {
        *(float4*)&el[row_ * NH] = make_float4(seh[0], seh[1], seh[2], seh[3]);
        *(float4*)&er[row_ * NH] = make_float4(srh[0], srh[1], srh[2], srh[3]);
      }
    }
  }
}

// ============================ softmax (alpha precompute) ============================
// One wave per dst node; in-register phases; stores alpha[head][E] fp32.
__global__ __launch_bounds__(256) void k_softmax(const float* __restrict__ el,
                                                 const float* __restrict__ er,
                                                 const int* __restrict__ rstart,
                                                 const int* __restrict__ degs,
                                                 const int* __restrict__ csr_src,
                                                 float* __restrict__ alpha) {
  int node = blockIdx.x * 4 + (threadIdx.x >> 6);
  if (node >= NN) return;
  int lane = threadIdx.x & 63;
  int start = rstart[node];
  int deg = degs[node];
  if (deg == 0) return;

  float ern = er[node * NH + (lane & 3)];

  int sreg[4];
  float ereg[4];
  float mloc = -INFINITY;
#pragma unroll
  for (int c = 0; c < 4; ++c) {
    int j = c * 16 + (lane >> 2);
    int s = 0;
    float e = -INFINITY;
    if (c * 16 < deg && j < deg) {
      s = csr_src[start + j];
      e = el[s * NH + (lane & 3)] + ern;
      e = (e >= 0.f) ? e : NEG_SLOPE * e;
    }
    sreg[c] = s;
    ereg[c] = e;
    mloc = fmaxf(mloc, e);
  }
  for (int j0 = 64; j0 < deg; j0 += 16) {  // rare tail
    int j = j0 + (lane >> 2);
    if (j < deg) {
      int s = csr_src[start + j];
      float e = el[s * NH + (lane & 3)] + ern;
      e = (e >= 0.f) ? e : NEG_SLOPE * e;
      mloc = fmaxf(mloc, e);
    }
  }
  float mm = mloc;
#pragma unroll
  for (int off = 4; off < 64; off <<= 1) mm = fmaxf(mm, __shfl_xor(mm, off));

  float vreg[4];
  float vloc = 0.f;
#pragma unroll
  for (int c = 0; c < 4; ++c) {
    float v = (ereg[c] > -INFINITY) ? __expf(ereg[c] - mm) : 0.f;
    vreg[c] = v;
    vloc += v;
  }
  for (int j0 = 64; j0 < deg; j0 += 16) {  // rare tail
    int j = j0 + (lane >> 2);
    if (j < deg) {
      int s = csr_src[start + j];
      float e = el[s * NH + (lane & 3)] + ern;
      e = (e >= 0.f) ? e : NEG_SLOPE * e;
      vloc += __expf(e - mm);
    }
  }
  float ss = vloc;
#pragma unroll
  for (int off = 4; off < 64; off <<= 1) ss += __shfl_xor(ss, off);

  float inv_own = (ss > 0.f) ? (1.f / ss) : 0.f;

#pragma unroll
  for (int c = 0; c < 4; ++c) {
    int j = c * 16 + (lane >> 2);
    if (c * 16 < deg && j < deg)
      alpha[(size_t)(lane & 3) * EE + start + j] = vreg[c] * inv_own;
  }
  for (int j0 = 64; j0 < deg; j0 += 16) {  // rare tail
    int j = j0 + (lane >> 2);
    if (j < deg) {
      int s = csr_src[start + j];
      float e = el[s * NH + (lane & 3)] + ern;
      e = (e >= 0.f) ? e : NEG_SLOPE * e;
      alpha[(size_t)(lane & 3) * EE + start + j] = __expf(e - mm) * inv_own;
    }
  }
}

// ============================ gather (XCD-sliced, wave/(node,slice)) ============================
// Block b: slice s=b&7 (-> XCD via round-robin), 4 nodes (one per wave).
// Wave iteration: 8 edges; lane = (edge eg=lane>>3, featgroup fl=lane&7).
// Loads/iter: csr 4B (8-lane broadcast), alpha 4B (broadcast), f 8B -> 512B/wave.
__global__ __launch_bounds__(256) void k_gather(const __bf16* __restrict__ fsl,
                                                const float* __restrict__ alpha,
                                                const int* __restrict__ rstart,
                                                const int* __restrict__ degs,
                                                const int* __restrict__ csr_src,
                                                const float* __restrict__ bias,
                                                float* __restrict__ out, int act) {
  int b = blockIdx.x;
  int s = b & 7;
  int node = (b >> 3) * 4 + (threadIdx.x >> 6);
  if (node >= NN) return;
  int lane = threadIdx.x & 63;
  int eg = lane >> 3;
  int fl = lane & 7;

  int start = rstart[node];
  int deg = degs[node];
  const __bf16* fbase = fsl + (size_t)s * NN * 32;
  const float* abase = alpha + (size_t)(s >> 1) * EE;

  float a0 = 0.f, a1 = 0.f, a2 = 0.f, a3 = 0.f;
  for (int j0 = 0; j0 < deg; j0 += 8) {
    int j = j0 + eg;
    int jc = (j < deg) ? j : (deg - 1);   // clamp: duplicate edge, a=0
    int srcn = csr_src[start + jc];
    float a = (j < deg) ? abase[start + jc] : 0.f;
    ushort4 u = *(const ushort4*)(fbase + (size_t)srcn * 32 + fl * 4);
    a0 = fmaf(a, bf2f(u.x), a0);
    a1 = fmaf(a, bf2f(u.y), a1);
    a2 = fmaf(a, bf2f(u.z), a2);
    a3 = fmaf(a, bf2f(u.w), a3);
  }
#pragma unroll
  for (int m = 8; m < 64; m <<= 1) {
    a0 += __shfl_xor(a0, m);
    a1 += __shfl_xor(a1, m);
    a2 += __shfl_xor(a2, m);
    a3 += __shfl_xor(a3, m);
  }
  if (eg == 0) {
    float4 bv = ((const float4*)bias)[s * 8 + fl];
    float4 r;
    r.x = a0 + bv.x;
    r.y = a1 + bv.y;
    r.z = a2 + bv.z;
    r.w = a3 + bv.w;
    if (act) {
      r.x = (r.x > 0.f) ? r.x : __expf(r.x) - 1.f;
      r.y = (r.y > 0.f) ? r.y : __expf(r.y) - 1.f;
      r.z = (r.z > 0.f) ? r.z : __expf(r.z) - 1.f;
      r.w = (r.w > 0.f) ? r.w : __expf(r.w) - 1.f;
    }
    ((float4*)(out + (size_t)node * HD + s * 32))[fl] = r;
  }
}

// ============================ launch ============================
extern "C" void kernel_launch(void* const* d_in, const int* in_sizes, int n_in,
                              void* d_out, int out_size, void* d_ws, size_t ws_size,
                              hipStream_t stream) {
  const int* nids = (const int*)d_in[0];
  const int* esrc = (const int*)d_in[1];
  const int* edst = (const int*)d_in[2];
  const float* emb = (const float*)d_in[3];
  const float* W1 = (const float*)d_in[4];
  const float* al1 = (const float*)d_in[5];
  const float* ar1 = (const float*)d_in[6];
  const float* b1 = (const float*)d_in[7];
  const float* W2 = (const float*)d_in[8];
  const float* al2 = (const float*)d_in[9];
  const float* ar2 = (const float*)d_in[10];
  const float* b2 = (const float*)d_in[11];
  float* out = (float*)d_out;

  char* w = (char*)d_ws;
  size_t off = 0;
  auto alloc = [&](size_t bytes) {
    void* p = w + off;
    off += (bytes + 255) & ~(size_t)255;
    return p;
  };
  __bf16* fsl = (__bf16*)alloc((size_t)NN * HD * 2);       // [8][NN][32]
  float* el = (float*)alloc((size_t)NN * NH * 4);
  float* er = (float*)alloc((size_t)NN * NH * 4);
  float* alpha = (float*)alloc((size_t)NH * EE * 4);       // [4][EE]
  int* rstart = (int*)alloc((size_t)NN * 4);
  int* counts = (int*)alloc((size_t)(NN + 8) * 4);         // +counter
  int* total = counts + NN;
  int* rank = (int*)alloc((size_t)EE * 4);
  int* csr_src = (int*)alloc((size_t)EE * 4);
  _Float16* W1t = (_Float16*)alloc((size_t)HD * HD * 2);
  _Float16* W2t = (_Float16*)alloc((size_t)HD * HD * 2);

  int nbE = (EE + 255) / 256;

  k_zero_i32<<<(NN + 8 + 255) / 256, 256, 0, stream>>>(counts, NN + 8);
  k_count<<<nbE, 256, 0, stream>>>(edst, counts, rank);
  k_alloc<<<(NN + 255) / 256, 256, 0, stream>>>(counts, rstart, total);
  k_scatter<<<nbE, 256, 0, stream>>>(esrc, edst, rstart, rank, csr_src);
  k_prep_w2<<<512, 256, 0, stream>>>(W1, W2, W1t, W2t);

  int nbNode4 = (NN + 3) / 4;
  int gatherGrid = nbNode4 * 8;   // 100000 (multiple of 8)

  // ---- layer 1 ----
  k_gemm_mfma<<<256, 768, 0, stream>>>(emb, nids, W1t, al1, ar1, fsl, el, er);
  k_softmax<<<nbNode4, 256, 0, stream>>>(el, er, rstart, counts, csr_src, alpha);
  k_gather<<<gatherGrid, 256, 0, stream>>>(fsl, alpha, rstart, counts, csr_src, b1, out, 1);

  // ---- layer 2 ----
  k_gemm_mfma<<<256, 768, 0, stream>>>(out, nullptr, W2t, al2, ar2, fsl, el, er);
  k_softmax<<<nbNode4, 256, 0, stream>>>(el, er, rstart, counts, csr_src, alpha);
  k_gather<<<gatherGrid, 256, 0, stream>>>(fsl, alpha, rstart, counts, csr_src, b2, out, 0);
}

// Round 12
// 180.288 us; speedup vs baseline: 2.1122x; 2.1122x over previous
//
#include <hip/hip_runtime.h>
#include <math.h>

#define NN 50000
#define EE 400000
#define HD 256
#define NH 4
#define DH 64
#define NEG_SLOPE 0.2f
#define NTILES 3125   // 50000/16 exact

typedef __attribute__((ext_vector_type(8))) _Float16 f16x8;
typedef __attribute__((ext_vector_type(4))) float f32x4;

__device__ __forceinline__ float bf2f(unsigned short h) {
  return __uint_as_float(((unsigned)h) << 16);
}
__device__ __forceinline__ unsigned short f2bf(float x) {
  __bf16 b = (__bf16)x;
  return *(unsigned short*)&b;
}

// ============================ CSR build (scan-free) ============================
__global__ void k_zero_i32(int* __restrict__ p, int n) {
  int i = blockIdx.x * blockDim.x + threadIdx.x;
  if (i < n) p[i] = 0;
}

__global__ void k_count(const int* __restrict__ dst, int* __restrict__ counts,
                        int* __restrict__ rank) {
  int e = blockIdx.x * blockDim.x + threadIdx.x;
  if (e < EE) rank[e] = atomicAdd(&counts[dst[e]], 1);
}

__global__ void k_alloc(const int* __restrict__ counts, int* __restrict__ rstart,
                        int* __restrict__ total) {
  int i = blockIdx.x * blockDim.x + threadIdx.x;
  if (i < NN) rstart[i] = atomicAdd(total, counts[i]);
}

__global__ void k_scatter(const int* __restrict__ src, const int* __restrict__ dst,
                          const int* __restrict__ rstart, const int* __restrict__ rank,
                          int* __restrict__ csr_src) {
  int e = blockIdx.x * blockDim.x + threadIdx.x;
  if (e < EE) csr_src[rstart[dst[e]] + rank[e]] = src[e];
}

// ============================ W prep (fp16, pre-tiled) ============================
__global__ __launch_bounds__(256) void k_prep_w2(const float* __restrict__ W1,
                                                 const float* __restrict__ W2,
                                                 _Float16* __restrict__ W1t,
                                                 _Float16* __restrict__ W2t) {
  int b = blockIdx.x;
  const float* W = (b < 256) ? W1 : W2;
  _Float16* Wt = (b < 256) ? W1t : W2t;
  int t = (b & 255) * 256 + threadIdx.x;  // 65536
  int n = t & 255, k = t >> 8;
  float x = W[(size_t)k * 256 + n];
  size_t o = (size_t)(k >> 5) * 8192 + (size_t)((k >> 3) & 3) * 2048 + (size_t)n * 8 + (k & 7);
  Wt[o] = (_Float16)x;
}

// ============================ MFMA GEMM ============================
// f[M,256](bf16) = A[idx[m],256] @ W.
// ABF16=0: A fp32, fp16-split (Ah+Al)@W (2 MFMA terms).
// ABF16=1: A bf16 -> fp16 conversion is EXACT -> single MFMA term.
// Whole W (128KB fp16, pre-tiled) in LDS, staged once, ONE barrier.
__device__ __forceinline__ void gload_lds16(const void* g, void* l) {
  __builtin_amdgcn_global_load_lds((const __attribute__((address_space(1))) void*)g,
                                   (__attribute__((address_space(3))) void*)l, 16, 0, 0);
}

template <int ABF16>
__global__ __launch_bounds__(768, 3) void k_gemm_mfma(
    const void* __restrict__ Av, const int* __restrict__ idx,
    const _Float16* __restrict__ Wt,
    const float* __restrict__ al, const float* __restrict__ ar,
    __bf16* __restrict__ C, float* __restrict__ el, float* __restrict__ er) {
  __shared__ f16x8 Bs[8192];  // 128KB

  int tid = threadIdx.x;
  int lane = tid & 63;
  int w = tid >> 6;           // 0..11
  int khalf = lane >> 4;
  int l15 = lane & 15;

  for (int i = tid; i < 8192; i += 768)
    gload_lds16(Wt + (size_t)i * 8, (void*)&Bs[i]);

  float alv[16], arv[16];
#pragma unroll
  for (int nf = 0; nf < 16; ++nf) {
    alv[nf] = al[nf * 16 + l15];
    arv[nf] = ar[nf * 16 + l15];
  }

  int nt = 1;
  int tiles[2];
  tiles[0] = blockIdx.x * 12 + w;
  int t2 = 3072 + blockIdx.x;
  if (w == 0 && t2 < NTILES) { tiles[1] = t2; nt = 2; }

  __syncthreads();  // the only barrier

  for (int it = 0; it < nt; ++it) {
    int t = tiles[it];
    int row = t * 16 + l15;
    int arow = idx ? idx[row] : row;

    f32x4 acc[16];
#pragma unroll
    for (int nf = 0; nf < 16; ++nf) acc[nf] = (f32x4){0.f, 0.f, 0.f, 0.f};

    if (ABF16) {
      const __bf16* ap = (const __bf16*)Av + (size_t)arow * HD + khalf * 8;
#pragma unroll 2
      for (int kb = 0; kb < 8; ++kb) {
        ushort4 uv = *(const ushort4*)(ap + kb * 32);   // 8 bf16 = 16B? (4x u16x?) -> need 8
        ushort4 uv2 = *(const ushort4*)(ap + kb * 32 + 4);
        f16x8 ah;
        ah[0] = (_Float16)bf2f(uv.x);
        ah[1] = (_Float16)bf2f(uv.y);
        ah[2] = (_Float16)bf2f(uv.z);
        ah[3] = (_Float16)bf2f(uv.w);
        ah[4] = (_Float16)bf2f(uv2.x);
        ah[5] = (_Float16)bf2f(uv2.y);
        ah[6] = (_Float16)bf2f(uv2.z);
        ah[7] = (_Float16)bf2f(uv2.w);
#pragma unroll
        for (int nf = 0; nf < 16; ++nf) {
          f16x8 bv = Bs[kb * 1024 + khalf * 256 + nf * 16 + l15];
          acc[nf] = __builtin_amdgcn_mfma_f32_16x16x32_f16(ah, bv, acc[nf], 0, 0, 0);
        }
      }
    } else {
      const float* ap = (const float*)Av + (size_t)arow * HD + khalf * 8;
#pragma unroll 2
      for (int kb = 0; kb < 8; ++kb) {
        float xx[8];
        *(float4*)&xx[0] = *(const float4*)(ap + kb * 32);
        *(float4*)&xx[4] = *(const float4*)(ap + kb * 32 + 4);
        f16x8 ah, alo;
#pragma unroll
        for (int i = 0; i < 8; ++i) {
          _Float16 h = (_Float16)xx[i];
          ah[i] = h;
          alo[i] = (_Float16)(xx[i] - (float)h);
        }
#pragma unroll
        for (int nf = 0; nf < 16; ++nf) {
          f16x8 bv = Bs[kb * 1024 + khalf * 256 + nf * 16 + l15];
          acc[nf] = __builtin_amdgcn_mfma_f32_16x16x32_f16(ah, bv, acc[nf], 0, 0, 0);
          acc[nf] = __builtin_amdgcn_mfma_f32_16x16x32_f16(alo, bv, acc[nf], 0, 0, 0);
        }
      }
    }

    int rowbase = t * 16 + khalf * 4;
#pragma unroll
    for (int r = 0; r < 4; ++r) {
      int row_ = rowbase + r;
      float seh[4], srh[4];
#pragma unroll
      for (int h = 0; h < 4; ++h) {
        float s1 = 0.f, s2 = 0.f;
#pragma unroll
        for (int j = 0; j < 4; ++j) {
          int nf = h * 4 + j;
          float v = acc[nf][r];
          s1 = fmaf(v, alv[nf], s1);
          s2 = fmaf(v, arv[nf], s2);
          C[(size_t)row_ * HD + nf * 16 + l15] = (__bf16)v;
        }
#pragma unroll
        for (int off = 1; off < 16; off <<= 1) {
          s1 += __shfl_xor(s1, off);
          s2 += __shfl_xor(s2, off);
        }
        seh[h] = s1;
        srh[h] = s2;
      }
      if (l15 == 0) {
        *(float4*)&el[row_ * NH] = make_float4(seh[0], seh[1], seh[2], seh[3]);
        *(float4*)&er[row_ * NH] = make_float4(srh[0], srh[1], srh[2], srh[3]);
      }
    }
  }
}

// ============================ aggregation ============================
// One wave per dst node (r7/r10 proven): in-register softmax for deg<=64,
// 8-deep batched 8B/lane gather. OUTBF16: write bf16 (layer 1) vs fp32.
template <int OUTBF16>
__global__ __launch_bounds__(256) void k_aggregate(const __bf16* __restrict__ f,
                                                   const float* __restrict__ el,
                                                   const float* __restrict__ er,
                                                   const int* __restrict__ rstart,
                                                   const int* __restrict__ degs,
                                                   const int* __restrict__ csr_src,
                                                   const float* __restrict__ bias,
                                                   void* __restrict__ outv, int act) {
  int node = blockIdx.x * 4 + (threadIdx.x >> 6);
  if (node >= NN) return;
  int lane = threadIdx.x & 63;
  int start = rstart[node];
  int deg = degs[node];

  float ern = er[node * NH + (lane & 3)];

  int sreg[4];
  float ereg[4];
  float mloc = -INFINITY;
#pragma unroll
  for (int c = 0; c < 4; ++c) {
    int j = c * 16 + (lane >> 2);
    int s = 0;
    float e = -INFINITY;
    if (c * 16 < deg && j < deg) {
      s = csr_src[start + j];
      e = el[s * NH + (lane & 3)] + ern;
      e = (e >= 0.f) ? e : NEG_SLOPE * e;
    }
    sreg[c] = s;
    ereg[c] = e;
    mloc = fmaxf(mloc, e);
  }
  for (int j0 = 64; j0 < deg; j0 += 16) {  // rare tail
    int j = j0 + (lane >> 2);
    if (j < deg) {
      int s = csr_src[start + j];
      float e = el[s * NH + (lane & 3)] + ern;
      e = (e >= 0.f) ? e : NEG_SLOPE * e;
      mloc = fmaxf(mloc, e);
    }
  }
  float mm = mloc;
#pragma unroll
  for (int off = 4; off < 64; off <<= 1) mm = fmaxf(mm, __shfl_xor(mm, off));

  float vreg[4];
  float vloc = 0.f;
#pragma unroll
  for (int c = 0; c < 4; ++c) {
    float v = (ereg[c] > -INFINITY) ? __expf(ereg[c] - mm) : 0.f;
    vreg[c] = v;
    vloc += v;
  }
  for (int j0 = 64; j0 < deg; j0 += 16) {  // rare tail
    int j = j0 + (lane >> 2);
    if (j < deg) {
      int s = csr_src[start + j];
      float e = el[s * NH + (lane & 3)] + ern;
      e = (e >= 0.f) ? e : NEG_SLOPE * e;
      vloc += __expf(e - mm);
    }
  }
  float ss = vloc;
#pragma unroll
  for (int off = 4; off < 64; off <<= 1) ss += __shfl_xor(ss, off);

  float inv_own = (ss > 0.f) ? (1.f / ss) : 0.f;
  float areg[4];
#pragma unroll
  for (int c = 0; c < 4; ++c) areg[c] = vreg[c] * inv_own;

  int head = lane >> 4;

  float4 acc = ((const float4*)bias)[lane];
  for (int c = 0; c < 4; ++c) {
    int base = c * 16;
    if (base >= deg) break;
    int cnt = deg - base;
    cnt = (cnt > 16) ? 16 : cnt;
    for (int g = 0; g < cnt; g += 8) {
      ushort4 u[8];
      float aa[8];
#pragma unroll
      for (int jj = 0; jj < 8; ++jj) {
        int j = g + jj;
        int jc = (j < cnt) ? j : (cnt - 1);   // clamp: duplicate row, a=0
        int srcl = jc * 4 + head;
        int s = __shfl(sreg[c], srcl);
        float a = __shfl(areg[c], srcl);
        aa[jj] = (j < cnt) ? a : 0.f;
        u[jj] = ((const ushort4*)(f + (size_t)s * HD))[lane];
      }
#pragma unroll
      for (int jj = 0; jj < 8; ++jj) {
        acc.x = fmaf(aa[jj], bf2f(u[jj].x), acc.x);
        acc.y = fmaf(aa[jj], bf2f(u[jj].y), acc.y);
        acc.z = fmaf(aa[jj], bf2f(u[jj].z), acc.z);
        acc.w = fmaf(aa[jj], bf2f(u[jj].w), acc.w);
      }
    }
  }
  if (deg > 64) {  // rare tail
    float mH = __shfl(mm, head);
    float sH = __shfl(ss, head);
    float erH = __shfl(ern, head);
    float invH = (sH > 0.f) ? (1.f / sH) : 0.f;
    for (int j = 64; j < deg; ++j) {
      int s = csr_src[start + j];
      float e = el[s * NH + head] + erH;
      e = (e >= 0.f) ? e : NEG_SLOPE * e;
      float a = __expf(e - mH) * invH;
      ushort4 u = ((const ushort4*)(f + (size_t)s * HD))[lane];
      acc.x = fmaf(a, bf2f(u.x), acc.x);
      acc.y = fmaf(a, bf2f(u.y), acc.y);
      acc.z = fmaf(a, bf2f(u.z), acc.z);
      acc.w = fmaf(a, bf2f(u.w), acc.w);
    }
  }

  if (act) {
    acc.x = (acc.x > 0.f) ? acc.x : __expf(acc.x) - 1.f;
    acc.y = (acc.y > 0.f) ? acc.y : __expf(acc.y) - 1.f;
    acc.z = (acc.z > 0.f) ? acc.z : __expf(acc.z) - 1.f;
    acc.w = (acc.w > 0.f) ? acc.w : __expf(acc.w) - 1.f;
  }
  if (OUTBF16) {
    ushort4 st;
    st.x = f2bf(acc.x);
    st.y = f2bf(acc.y);
    st.z = f2bf(acc.z);
    st.w = f2bf(acc.w);
    ((ushort4*)((__bf16*)outv + (size_t)node * HD))[lane] = st;
  } else {
    ((float4*)((float*)outv + (size_t)node * HD))[lane] = acc;
  }
}

// ============================ launch ============================
extern "C" void kernel_launch(void* const* d_in, const int* in_sizes, int n_in,
                              void* d_out, int out_size, void* d_ws, size_t ws_size,
                              hipStream_t stream) {
  const int* nids = (const int*)d_in[0];
  const int* esrc = (const int*)d_in[1];
  const int* edst = (const int*)d_in[2];
  const float* emb = (const float*)d_in[3];
  const float* W1 = (const float*)d_in[4];
  const float* al1 = (const float*)d_in[5];
  const float* ar1 = (const float*)d_in[6];
  const float* b1 = (const float*)d_in[7];
  const float* W2 = (const float*)d_in[8];
  const float* al2 = (const float*)d_in[9];
  const float* ar2 = (const float*)d_in[10];
  const float* b2 = (const float*)d_in[11];
  float* out = (float*)d_out;

  char* w = (char*)d_ws;
  size_t off = 0;
  auto alloc = [&](size_t bytes) {
    void* p = w + off;
    off += (bytes + 255) & ~(size_t)255;
    return p;
  };
  __bf16* fbuf = (__bf16*)alloc((size_t)NN * HD * 2);
  __bf16* hbuf = (__bf16*)alloc((size_t)NN * HD * 2);   // layer-1 output (bf16)
  float* el = (float*)alloc((size_t)NN * NH * 4);
  float* er = (float*)alloc((size_t)NN * NH * 4);
  int* rstart = (int*)alloc((size_t)NN * 4);
  int* counts = (int*)alloc((size_t)(NN + 8) * 4);   // +counter
  int* total = counts + NN;
  int* rank = (int*)alloc((size_t)EE * 4);
  int* csr_src = (int*)alloc((size_t)EE * 4);
  _Float16* W1t = (_Float16*)alloc((size_t)HD * HD * 2);
  _Float16* W2t = (_Float16*)alloc((size_t)HD * HD * 2);

  int nbE = (EE + 255) / 256;

  k_zero_i32<<<(NN + 8 + 255) / 256, 256, 0, stream>>>(counts, NN + 8);
  k_count<<<nbE, 256, 0, stream>>>(edst, counts, rank);
  k_alloc<<<(NN + 255) / 256, 256, 0, stream>>>(counts, rstart, total);
  k_scatter<<<nbE, 256, 0, stream>>>(esrc, edst, rstart, rank, csr_src);
  k_prep_w2<<<512, 256, 0, stream>>>(W1, W2, W1t, W2t);

  int nbNode4 = (NN + 3) / 4;

  // ---- layer 1 ----
  k_gemm_mfma<0><<<256, 768, 0, stream>>>(emb, nids, W1t, al1, ar1, fbuf, el, er);
  k_aggregate<1><<<nbNode4, 256, 0, stream>>>(fbuf, el, er, rstart, counts, csr_src, b1, hbuf, 1);

  // ---- layer 2 ----
  k_gemm_mfma<1><<<256, 768, 0, stream>>>(hbuf, nullptr, W2t, al2, ar2, fbuf, el, er);
  k_aggregate<0><<<nbNode4, 256, 0, stream>>>(fbuf, el, er, rstart, counts, csr_src, b2, out, 0);
}

// Round 13
// 173.467 us; speedup vs baseline: 2.1952x; 1.0393x over previous
//
#include <hip/hip_runtime.h>
#include <math.h>

#define NN 50000
#define EE 400000
#define HD 256
#define NH 4
#define DH 64
#define NEG_SLOPE 0.2f
#define NTILES 3125   // 50000/16 exact

typedef __attribute__((ext_vector_type(8))) _Float16 f16x8;
typedef __attribute__((ext_vector_type(4))) float f32x4;

__device__ __forceinline__ float bf2f(unsigned short h) {
  return __uint_as_float(((unsigned)h) << 16);
}
__device__ __forceinline__ unsigned short f2bf(float x) {
  __bf16 b = (__bf16)x;
  return *(unsigned short*)&b;
}

// ============================ init: zero counts + W prep (fused) ============================
// blocks 0..195: zero counts[NN+8]; blocks 196..707: pre-tile W1/W2 to fp16.
__global__ __launch_bounds__(256) void k_init(int* __restrict__ counts,
                                              const float* __restrict__ W1,
                                              const float* __restrict__ W2,
                                              _Float16* __restrict__ W1t,
                                              _Float16* __restrict__ W2t) {
  int b = blockIdx.x;
  if (b < 196) {
    int i = b * 256 + threadIdx.x;
    if (i < NN + 8) counts[i] = 0;
  } else {
    int bb = b - 196;  // 0..511
    const float* W = (bb < 256) ? W1 : W2;
    _Float16* Wt = (bb < 256) ? W1t : W2t;
    int t = (bb & 255) * 256 + threadIdx.x;  // 65536
    int n = t & 255, k = t >> 8;
    float x = W[(size_t)k * 256 + n];
    size_t o = (size_t)(k >> 5) * 8192 + (size_t)((k >> 3) & 3) * 2048 + (size_t)n * 8 + (k & 7);
    Wt[o] = (_Float16)x;
  }
}

// ============================ CSR build (scan-free) ============================
__global__ void k_count(const int* __restrict__ dst, int* __restrict__ counts,
                        int* __restrict__ rank) {
  int e = blockIdx.x * blockDim.x + threadIdx.x;
  if (e < EE) rank[e] = atomicAdd(&counts[dst[e]], 1);
}

__global__ void k_alloc(const int* __restrict__ counts, int* __restrict__ rstart,
                        int* __restrict__ total) {
  int i = blockIdx.x * blockDim.x + threadIdx.x;
  if (i < NN) rstart[i] = atomicAdd(total, counts[i]);
}

__global__ void k_scatter(const int* __restrict__ src, const int* __restrict__ dst,
                          const int* __restrict__ rstart, const int* __restrict__ rank,
                          int* __restrict__ csr_src) {
  int e = blockIdx.x * blockDim.x + threadIdx.x;
  if (e < EE) csr_src[rstart[dst[e]] + rank[e]] = src[e];
}

// ============================ MFMA GEMM ============================
// f[M,256](bf16) = A[idx[m],256] @ W.
// ABF16=0: A fp32, fp16-split (Ah+Al)@W (2 MFMA terms).
// ABF16=1: A bf16 -> fp16 exact -> single MFMA term.
// Whole W (128KB fp16, pre-tiled) in LDS, staged once, ONE barrier.
// 1024 threads / 16 waves (4/SIMD), one 16-row tile per wave, grid 196.
// Explicit register prefetch of A(kb+1) hides load latency under MFMA.
__device__ __forceinline__ void gload_lds16(const void* g, void* l) {
  __builtin_amdgcn_global_load_lds((const __attribute__((address_space(1))) void*)g,
                                   (__attribute__((address_space(3))) void*)l, 16, 0, 0);
}

template <int ABF16>
__global__ __launch_bounds__(1024, 4) void k_gemm_mfma(
    const void* __restrict__ Av, const int* __restrict__ idx,
    const _Float16* __restrict__ Wt,
    const float* __restrict__ al, const float* __restrict__ ar,
    __bf16* __restrict__ C, float* __restrict__ el, float* __restrict__ er) {
  __shared__ f16x8 Bs[8192];  // 128KB

  int tid = threadIdx.x;
  int lane = tid & 63;
  int w = tid >> 6;           // 0..15
  int khalf = lane >> 4;
  int l15 = lane & 15;

  for (int i = tid; i < 8192; i += 1024)
    gload_lds16(Wt + (size_t)i * 8, (void*)&Bs[i]);

  float alv[16], arv[16];
#pragma unroll
  for (int nf = 0; nf < 16; ++nf) {
    alv[nf] = al[nf * 16 + l15];
    arv[nf] = ar[nf * 16 + l15];
  }

  int t = blockIdx.x * 16 + w;   // 196*16 = 3136 >= 3125
  bool active = t < NTILES;

  __syncthreads();  // the only barrier

  if (active) {
    int row = t * 16 + l15;
    int arow = idx ? idx[row] : row;

    f32x4 acc[16];
#pragma unroll
    for (int nf = 0; nf < 16; ++nf) acc[nf] = (f32x4){0.f, 0.f, 0.f, 0.f};

    if (ABF16) {
      const __bf16* ap = (const __bf16*)Av + (size_t)arow * HD + khalf * 8;
      uint4 cur = *(const uint4*)(ap);          // 8 bf16 = 16B
#pragma unroll
      for (int kb = 0; kb < 8; ++kb) {
        uint4 nxt;
        if (kb < 7) nxt = *(const uint4*)(ap + (kb + 1) * 32);
        const unsigned* uu = (const unsigned*)&cur;
        f16x8 ah;
#pragma unroll
        for (int i = 0; i < 4; ++i) {
          ah[2 * i] = (_Float16)__uint_as_float(uu[i] << 16);
          ah[2 * i + 1] = (_Float16)__uint_as_float(uu[i] & 0xffff0000u);
        }
#pragma unroll
        for (int nf = 0; nf < 16; ++nf) {
          f16x8 bv = Bs[kb * 1024 + khalf * 256 + nf * 16 + l15];
          acc[nf] = __builtin_amdgcn_mfma_f32_16x16x32_f16(ah, bv, acc[nf], 0, 0, 0);
        }
        cur = nxt;
      }
    } else {
      const float* ap = (const float*)Av + (size_t)arow * HD + khalf * 8;
      float4 c0 = *(const float4*)(ap);
      float4 c1 = *(const float4*)(ap + 4);
#pragma unroll
      for (int kb = 0; kb < 8; ++kb) {
        float4 n0, n1;
        if (kb < 7) {
          n0 = *(const float4*)(ap + (kb + 1) * 32);
          n1 = *(const float4*)(ap + (kb + 1) * 32 + 4);
        }
        float xx[8];
        *(float4*)&xx[0] = c0;
        *(float4*)&xx[4] = c1;
        f16x8 ah, alo;
#pragma unroll
        for (int i = 0; i < 8; ++i) {
          _Float16 h = (_Float16)xx[i];
          ah[i] = h;
          alo[i] = (_Float16)(xx[i] - (float)h);
        }
#pragma unroll
        for (int nf = 0; nf < 16; ++nf) {
          f16x8 bv = Bs[kb * 1024 + khalf * 256 + nf * 16 + l15];
          acc[nf] = __builtin_amdgcn_mfma_f32_16x16x32_f16(ah, bv, acc[nf], 0, 0, 0);
          acc[nf] = __builtin_amdgcn_mfma_f32_16x16x32_f16(alo, bv, acc[nf], 0, 0, 0);
        }
        c0 = n0;
        c1 = n1;
      }
    }

    int rowbase = t * 16 + khalf * 4;
#pragma unroll
    for (int r = 0; r < 4; ++r) {
      int row_ = rowbase + r;
      float seh[4], srh[4];
#pragma unroll
      for (int h = 0; h < 4; ++h) {
        float s1 = 0.f, s2 = 0.f;
#pragma unroll
        for (int j = 0; j < 4; ++j) {
          int nf = h * 4 + j;
          float v = acc[nf][r];
          s1 = fmaf(v, alv[nf], s1);
          s2 = fmaf(v, arv[nf], s2);
          C[(size_t)row_ * HD + nf * 16 + l15] = (__bf16)v;
        }
#pragma unroll
        for (int off = 1; off < 16; off <<= 1) {
          s1 += __shfl_xor(s1, off);
          s2 += __shfl_xor(s2, off);
        }
        seh[h] = s1;
        srh[h] = s2;
      }
      if (l15 == 0) {
        *(float4*)&el[row_ * NH] = make_float4(seh[0], seh[1], seh[2], seh[3]);
        *(float4*)&er[row_ * NH] = make_float4(srh[0], srh[1], srh[2], srh[3]);
      }
    }
  }
}

// ============================ aggregation ============================
// One wave per dst node (proven r7/r10/r12 structure). OUTBF16 for layer 1.
template <int OUTBF16>
__global__ __launch_bounds__(256) void k_aggregate(const __bf16* __restrict__ f,
                                                   const float* __restrict__ el,
                                                   const float* __restrict__ er,
                                                   const int* __restrict__ rstart,
                                                   const int* __restrict__ degs,
                                                   const int* __restrict__ csr_src,
                                                   const float* __restrict__ bias,
                                                   void* __restrict__ outv, int act) {
  int node = blockIdx.x * 4 + (threadIdx.x >> 6);
  if (node >= NN) return;
  int lane = threadIdx.x & 63;
  int start = rstart[node];
  int deg = degs[node];

  float ern = er[node * NH + (lane & 3)];

  int sreg[4];
  float ereg[4];
  float mloc = -INFINITY;
#pragma unroll
  for (int c = 0; c < 4; ++c) {
    int j = c * 16 + (lane >> 2);
    int s = 0;
    float e = -INFINITY;
    if (c * 16 < deg && j < deg) {
      s = csr_src[start + j];
      e = el[s * NH + (lane & 3)] + ern;
      e = (e >= 0.f) ? e : NEG_SLOPE * e;
    }
    sreg[c] = s;
    ereg[c] = e;
    mloc = fmaxf(mloc, e);
  }
  for (int j0 = 64; j0 < deg; j0 += 16) {  // rare tail
    int j = j0 + (lane >> 2);
    if (j < deg) {
      int s = csr_src[start + j];
      float e = el[s * NH + (lane & 3)] + ern;
      e = (e >= 0.f) ? e : NEG_SLOPE * e;
      mloc = fmaxf(mloc, e);
    }
  }
  float mm = mloc;
#pragma unroll
  for (int off = 4; off < 64; off <<= 1) mm = fmaxf(mm, __shfl_xor(mm, off));

  float vreg[4];
  float vloc = 0.f;
#pragma unroll
  for (int c = 0; c < 4; ++c) {
    float v = (ereg[c] > -INFINITY) ? __expf(ereg[c] - mm) : 0.f;
    vreg[c] = v;
    vloc += v;
  }
  for (int j0 = 64; j0 < deg; j0 += 16) {  // rare tail
    int j = j0 + (lane >> 2);
    if (j < deg) {
      int s = csr_src[start + j];
      float e = el[s * NH + (lane & 3)] + ern;
      e = (e >= 0.f) ? e : NEG_SLOPE * e;
      vloc += __expf(e - mm);
    }
  }
  float ss = vloc;
#pragma unroll
  for (int off = 4; off < 64; off <<= 1) ss += __shfl_xor(ss, off);

  float inv_own = (ss > 0.f) ? (1.f / ss) : 0.f;
  float areg[4];
#pragma unroll
  for (int c = 0; c < 4; ++c) areg[c] = vreg[c] * inv_own;

  int head = lane >> 4;

  float4 acc = ((const float4*)bias)[lane];
  for (int c = 0; c < 4; ++c) {
    int base = c * 16;
    if (base >= deg) break;
    int cnt = deg - base;
    cnt = (cnt > 16) ? 16 : cnt;
    for (int g = 0; g < cnt; g += 8) {
      ushort4 u[8];
      float aa[8];
#pragma unroll
      for (int jj = 0; jj < 8; ++jj) {
        int j = g + jj;
        int jc = (j < cnt) ? j : (cnt - 1);   // clamp: duplicate row, a=0
        int srcl = jc * 4 + head;
        int s = __shfl(sreg[c], srcl);
        float a = __shfl(areg[c], srcl);
        aa[jj] = (j < cnt) ? a : 0.f;
        u[jj] = ((const ushort4*)(f + (size_t)s * HD))[lane];
      }
#pragma unroll
      for (int jj = 0; jj < 8; ++jj) {
        acc.x = fmaf(aa[jj], bf2f(u[jj].x), acc.x);
        acc.y = fmaf(aa[jj], bf2f(u[jj].y), acc.y);
        acc.z = fmaf(aa[jj], bf2f(u[jj].z), acc.z);
        acc.w = fmaf(aa[jj], bf2f(u[jj].w), acc.w);
      }
    }
  }
  if (deg > 64) {  // rare tail
    float mH = __shfl(mm, head);
    float sH = __shfl(ss, head);
    float erH = __shfl(ern, head);
    float invH = (sH > 0.f) ? (1.f / sH) : 0.f;
    for (int j = 64; j < deg; ++j) {
      int s = csr_src[start + j];
      float e = el[s * NH + head] + erH;
      e = (e >= 0.f) ? e : NEG_SLOPE * e;
      float a = __expf(e - mH) * invH;
      ushort4 u = ((const ushort4*)(f + (size_t)s * HD))[lane];
      acc.x = fmaf(a, bf2f(u.x), acc.x);
      acc.y = fmaf(a, bf2f(u.y), acc.y);
      acc.z = fmaf(a, bf2f(u.z), acc.z);
      acc.w = fmaf(a, bf2f(u.w), acc.w);
    }
  }

  if (act) {
    acc.x = (acc.x > 0.f) ? acc.x : __expf(acc.x) - 1.f;
    acc.y = (acc.y > 0.f) ? acc.y : __expf(acc.y) - 1.f;
    acc.z = (acc.z > 0.f) ? acc.z : __expf(acc.z) - 1.f;
    acc.w = (acc.w > 0.f) ? acc.w : __expf(acc.w) - 1.f;
  }
  if (OUTBF16) {
    ushort4 st;
    st.x = f2bf(acc.x);
    st.y = f2bf(acc.y);
    st.z = f2bf(acc.z);
    st.w = f2bf(acc.w);
    ((ushort4*)((__bf16*)outv + (size_t)node * HD))[lane] = st;
  } else {
    ((float4*)((float*)outv + (size_t)node * HD))[lane] = acc;
  }
}

// ============================ launch ============================
extern "C" void kernel_launch(void* const* d_in, const int* in_sizes, int n_in,
                              void* d_out, int out_size, void* d_ws, size_t ws_size,
                              hipStream_t stream) {
  const int* nids = (const int*)d_in[0];
  const int* esrc = (const int*)d_in[1];
  const int* edst = (const int*)d_in[2];
  const float* emb = (const float*)d_in[3];
  const float* W1 = (const float*)d_in[4];
  const float* al1 = (const float*)d_in[5];
  const float* ar1 = (const float*)d_in[6];
  const float* b1 = (const float*)d_in[7];
  const float* W2 = (const float*)d_in[8];
  const float* al2 = (const float*)d_in[9];
  const float* ar2 = (const float*)d_in[10];
  const float* b2 = (const float*)d_in[11];
  float* out = (float*)d_out;

  char* w = (char*)d_ws;
  size_t off = 0;
  auto alloc = [&](size_t bytes) {
    void* p = w + off;
    off += (bytes + 255) & ~(size_t)255;
    return p;
  };
  __bf16* fbuf = (__bf16*)alloc((size_t)NN * HD * 2);
  __bf16* hbuf = (__bf16*)alloc((size_t)NN * HD * 2);   // layer-1 output (bf16)
  float* el = (float*)alloc((size_t)NN * NH * 4);
  float* er = (float*)alloc((size_t)NN * NH * 4);
  int* rstart = (int*)alloc((size_t)NN * 4);
  int* counts = (int*)alloc((size_t)(NN + 8) * 4);   // +counter
  int* total = counts + NN;
  int* rank = (int*)alloc((size_t)EE * 4);
  int* csr_src = (int*)alloc((size_t)EE * 4);
  _Float16* W1t = (_Float16*)alloc((size_t)HD * HD * 2);
  _Float16* W2t = (_Float16*)alloc((size_t)HD * HD * 2);

  int nbE = (EE + 255) / 256;

  k_init<<<708, 256, 0, stream>>>(counts, W1, W2, W1t, W2t);
  k_count<<<nbE, 256, 0, stream>>>(edst, counts, rank);
  k_alloc<<<(NN + 255) / 256, 256, 0, stream>>>(counts, rstart, total);
  k_scatter<<<nbE, 256, 0, stream>>>(esrc, edst, rstart, rank, csr_src);

  int nbNode4 = (NN + 3) / 4;

  // ---- layer 1 ----
  k_gemm_mfma<0><<<196, 1024, 0, stream>>>(emb, nids, W1t, al1, ar1, fbuf, el, er);
  k_aggregate<1><<<nbNode4, 256, 0, stream>>>(fbuf, el, er, rstart, counts, csr_src, b1, hbuf, 1);

  // ---- layer 2 ----
  k_gemm_mfma<1><<<196, 1024, 0, stream>>>(hbuf, nullptr, W2t, al2, ar2, fbuf, el, er);
  k_aggregate<0><<<nbNode4, 256, 0, stream>>>(fbuf, el, er, rstart, counts, csr_src, b2, out, 0);
}